// Round 1
// baseline (580.077 us; speedup 1.0000x reference)
//
#include <hip/hip_runtime.h>
#include <math.h>

#define N_ 4096
#define D_ 768
#define P_ 100
#define PPAD 128
#define BM 64
#define BN 64
#define BK 16
#define NSPLIT 8
#define JT_PER_SPLIT ((N_ / BN) / NSPLIT) /* 8 */

// ---------------------------------------------------------------------------
// block-wide sum with broadcast (256 threads = 4 waves)
__device__ inline float block_sum_bcast(float v, float* sred, int tid) {
#pragma unroll
    for (int m = 32; m > 0; m >>= 1) v += __shfl_xor(v, m);
    if ((tid & 63) == 0) sred[tid >> 6] = v;
    __syncthreads();
    float r = sred[0] + sred[1] + sred[2] + sred[3];
    __syncthreads();
    return r;
}

// ---------------------------------------------------------------------------
// pre: sq[i] = ||x_i||^2 ; cn = row-normalized centers (padded to 128 rows);
// csq[p] = ||cn_p||^2 (1e30 for pad rows)
__global__ __launch_bounds__(256) void pre_kernel(
    const float* __restrict__ X, const float* __restrict__ C,
    float* __restrict__ sq, float* __restrict__ cn, float* __restrict__ csq) {
    __shared__ float sred[4];
    int row = blockIdx.x;
    int tid = threadIdx.x;
    if (row < N_) {
        const float* x = X + (size_t)row * D_;
        float s = 0.f;
        for (int d = tid; d < D_; d += 256) { float v = x[d]; s += v * v; }
        s = block_sum_bcast(s, sred, tid);
        if (tid == 0) sq[row] = s;
    } else {
        int p = row - N_;
        if (p < P_) {
            const float* c = C + (size_t)p * D_;
            float s = 0.f;
            for (int d = tid; d < D_; d += 256) { float v = c[d]; s += v * v; }
            s = block_sum_bcast(s, sred, tid);
            float rn = 1.0f / sqrtf(s);
            float s2 = 0.f;
            for (int d = tid; d < D_; d += 256) {
                float v = c[d] * rn;
                cn[(size_t)p * D_ + d] = v;
                s2 += v * v;
            }
            s2 = block_sum_bcast(s2, sred, tid);
            if (tid == 0) csq[p] = s2;
        } else {
            for (int d = tid; d < D_; d += 256) cn[(size_t)p * D_ + d] = 0.f;
            if (tid == 0) csq[p] = 1e30f;
        }
    }
}

// ---------------------------------------------------------------------------
// main fused GEMM + hardest-pos/neg reduction.
// grid = (NSPLIT+1, N_/BM). split<NSPLIT: 8 j-tiles of inputs each.
// split==NSPLIT: 2 tiles over padded normalized centers.
__global__ __launch_bounds__(256) void tile_kernel(
    const float* __restrict__ X, const int* __restrict__ T,
    const float* __restrict__ sq, const float* __restrict__ cn,
    const float* __restrict__ csq,
    float* __restrict__ ap_part, float* __restrict__ an_part,
    int* __restrict__ hn_part, float* __restrict__ minc) {
    __shared__ float As[BK][BM];
    __shared__ float Bs[BK][BN];

    const int it = blockIdx.y;
    const int split = blockIdx.x;
    const int i0 = it * BM;
    const int tid = threadIdx.x;
    const int tx = tid & 15;   // 4 output cols at tx*4
    const int ty = tid >> 4;   // 4 output rows at ty*4

    const bool is_center = (split == NSPLIT);
    const int ntiles = is_center ? (PPAD / BN) : JT_PER_SPLIT;
    const float* __restrict__ Bmat = is_center ? cn : X;

    float sqi[4]; int ti[4];
#pragma unroll
    for (int q = 0; q < 4; ++q) {
        int i = i0 + ty * 4 + q;
        sqi[q] = sq[i];
        ti[q] = T[i];
    }

    float ap[4], an[4], mc[4];
    int hn = 0;
#pragma unroll
    for (int q = 0; q < 4; ++q) { ap[q] = -1e30f; an[q] = 1e30f; mc[q] = 1e30f; }

    const int lrow = tid >> 2;          // 0..63
    const int lc4 = (tid & 3) * 4;      // 0,4,8,12

    for (int jt = 0; jt < ntiles; ++jt) {
        const int j0 = is_center ? jt * BN : (split * JT_PER_SPLIT + jt) * BN;
        float acc[4][4];
#pragma unroll
        for (int a = 0; a < 4; ++a)
#pragma unroll
            for (int b = 0; b < 4; ++b) acc[a][b] = 0.f;

        for (int kt = 0; kt < D_ / BK; ++kt) {
            const int k0 = kt * BK;
            float4 av = *reinterpret_cast<const float4*>(&X[(size_t)(i0 + lrow) * D_ + k0 + lc4]);
            float4 bv = *reinterpret_cast<const float4*>(&Bmat[(size_t)(j0 + lrow) * D_ + k0 + lc4]);
            __syncthreads();  // previous iteration's reads done
            As[lc4 + 0][lrow] = av.x; As[lc4 + 1][lrow] = av.y;
            As[lc4 + 2][lrow] = av.z; As[lc4 + 3][lrow] = av.w;
            Bs[lc4 + 0][lrow] = bv.x; Bs[lc4 + 1][lrow] = bv.y;
            Bs[lc4 + 2][lrow] = bv.z; Bs[lc4 + 3][lrow] = bv.w;
            __syncthreads();
#pragma unroll
            for (int k = 0; k < BK; ++k) {
                float4 a4 = *reinterpret_cast<const float4*>(&As[k][ty * 4]);
                float4 b4 = *reinterpret_cast<const float4*>(&Bs[k][tx * 4]);
                float ar[4] = {a4.x, a4.y, a4.z, a4.w};
                float br[4] = {b4.x, b4.y, b4.z, b4.w};
#pragma unroll
                for (int qr = 0; qr < 4; ++qr)
#pragma unroll
                    for (int qc = 0; qc < 4; ++qc)
                        acc[qr][qc] = fmaf(ar[qr], br[qc], acc[qr][qc]);
            }
        }

        // epilogue: fold this 64x64 tile into running reductions
        if (is_center) {
#pragma unroll
            for (int qc = 0; qc < 4; ++qc) {
                int j = j0 + tx * 4 + qc;
                float sqj = csq[j];
#pragma unroll
                for (int qr = 0; qr < 4; ++qr) {
                    float d2 = sqi[qr] + sqj - 2.0f * acc[qr][qc];
                    float d = fmaxf(sqrtf(fmaxf(d2, 0.0f)), 1e-12f);
                    mc[qr] = fminf(mc[qr], d);
                }
            }
        } else {
#pragma unroll
            for (int qc = 0; qc < 4; ++qc) {
                int j = j0 + tx * 4 + qc;
                float sqj = sq[j];
                int tj = T[j];
#pragma unroll
                for (int qr = 0; qr < 4; ++qr) {
                    float d2 = sqi[qr] + sqj - 2.0f * acc[qr][qc];
                    float d = sqrtf(fmaxf(d2, 1e-12f));
                    if (tj == ti[qr]) {
                        ap[qr] = fmaxf(ap[qr], d);
                    } else {
                        an[qr] = fminf(an[qr], d);
                        hn |= (1 << qr);
                    }
                }
            }
        }
    }

    // reduce across the 16 tx-lanes (within-wave butterfly)
#pragma unroll
    for (int m = 1; m < 16; m <<= 1) {
#pragma unroll
        for (int q = 0; q < 4; ++q) {
            ap[q] = fmaxf(ap[q], __shfl_xor(ap[q], m));
            an[q] = fminf(an[q], __shfl_xor(an[q], m));
            mc[q] = fminf(mc[q], __shfl_xor(mc[q], m));
        }
        hn |= __shfl_xor(hn, m);
    }

    if (tx == 0) {
#pragma unroll
        for (int q = 0; q < 4; ++q) {
            int i = i0 + ty * 4 + q;
            if (is_center) {
                minc[i] = mc[q];
            } else {
                ap_part[split * N_ + i] = ap[q];
                an_part[split * N_ + i] = an[q];
                hn_part[split * N_ + i] = (hn >> q) & 1;
            }
        }
    }
}

// ---------------------------------------------------------------------------
__global__ __launch_bounds__(256) void combine_kernel(
    const float* __restrict__ ap_part, const float* __restrict__ an_part,
    const int* __restrict__ hn_part, const float* __restrict__ minc,
    float* __restrict__ out) {
    __shared__ float red[256];
    float lsum = 0.f;
    for (int i = threadIdx.x; i < N_; i += 256) {
        float ap = -1e30f, an = 1e30f;
        int hn = 0;
#pragma unroll
        for (int s = 0; s < NSPLIT; ++s) {
            ap = fmaxf(ap, ap_part[s * N_ + i]);
            an = fminf(an, an_part[s * N_ + i]);
            hn |= hn_part[s * N_ + i];
        }
        float dan = hn ? an : (ap + 1.0f);
        dan = fminf(dan, minc[i]);
        lsum += fmaxf(0.0f, 1.0f + ap - dan);
    }
    red[threadIdx.x] = lsum;
    __syncthreads();
    for (int s = 128; s > 0; s >>= 1) {
        if (threadIdx.x < s) red[threadIdx.x] += red[threadIdx.x + s];
        __syncthreads();
    }
    if (threadIdx.x == 0) out[0] = red[0] / (float)N_;
}

// ---------------------------------------------------------------------------
extern "C" void kernel_launch(void* const* d_in, const int* in_sizes, int n_in,
                              void* d_out, int out_size, void* d_ws, size_t ws_size,
                              hipStream_t stream) {
    const float* X = (const float*)d_in[0];
    const int* T = (const int*)d_in[1];
    const float* C = (const float*)d_in[2];
    float* out = (float*)d_out;

    float* ws = (float*)d_ws;
    float* sq = ws;                    // 4096
    float* csq = ws + 4096;            // 128
    float* cn = ws + 4224;             // 128*768 = 98304
    float* ap_part = ws + 102528;      // 8*4096 = 32768
    float* an_part = ws + 135296;      // 32768
    int* hn_part = (int*)(ws + 168064);// 32768
    float* minc = ws + 200832;         // 4096   (end = 204928 floats = 819712 B)

    pre_kernel<<<N_ + PPAD, 256, 0, stream>>>(X, C, sq, cn, csq);
    dim3 grid(NSPLIT + 1, N_ / BM);
    tile_kernel<<<grid, 256, 0, stream>>>(X, T, sq, cn, csq, ap_part, an_part,
                                          hn_part, minc);
    combine_kernel<<<1, 256, 0, stream>>>(ap_part, an_part, hn_part, minc, out);
}

// Round 2
// 90.906 us; speedup vs baseline: 6.3810x; 6.3810x over previous
//
#include <hip/hip_runtime.h>
#include <math.h>

#define N_ 4096
#define D_ 768
#define P_ 100
#define PPAD 128
#define NJT (N_ / 128)          /* 32 j-tiles over X; tile index NJT = centers */
#define NSLOT (NJT * 2)         /* 64 partial slots (2 wave-cols per block) */

typedef __attribute__((ext_vector_type(8))) short short8;
typedef __attribute__((ext_vector_type(4))) float f32x4;

typedef const __attribute__((address_space(1))) void* gld_src_t;
typedef __attribute__((address_space(3))) void* gld_dst_t;
#define GLOAD16(g, d) __builtin_amdgcn_global_load_lds((gld_src_t)(g), (gld_dst_t)(d), 16, 0, 0)

// float -> bf16 (RNE)
__device__ inline unsigned short f2bf(float f) {
    union { float f; unsigned int u; } v; v.f = f;
    unsigned int u = v.u + 0x7fffu + ((v.u >> 16) & 1u);
    return (unsigned short)(u >> 16);
}

__device__ inline float block_sum_bcast(float v, float* sred, int tid) {
#pragma unroll
    for (int m = 32; m > 0; m >>= 1) v += __shfl_xor(v, m);
    if ((tid & 63) == 0) sred[tid >> 6] = v;
    __syncthreads();
    float r = sred[0] + sred[1] + sred[2] + sred[3];
    __syncthreads();
    return r;
}

// ---------------------------------------------------------------------------
// pre: sq[i]=||x_i||^2 (fp32), Xbf = bf16(X); cnbf = bf16(row-normalized C,
// padded to 128 rows with zeros), csq fp32 (1e30 for pads)
__global__ __launch_bounds__(256) void pre_kernel(
    const float* __restrict__ X, const float* __restrict__ C,
    float* __restrict__ sq, unsigned short* __restrict__ Xbf,
    unsigned short* __restrict__ cnbf, float* __restrict__ csq) {
    __shared__ float sred[4];
    int row = blockIdx.x;
    int tid = threadIdx.x;
    if (row < N_) {
        const float* x = X + (size_t)row * D_;
        float s = 0.f;
        for (int d = tid; d < D_; d += 256) {
            float v = x[d];
            s += v * v;
            Xbf[(size_t)row * D_ + d] = f2bf(v);
        }
        s = block_sum_bcast(s, sred, tid);
        if (tid == 0) sq[row] = s;
    } else {
        int p = row - N_;
        if (p < P_) {
            const float* c = C + (size_t)p * D_;
            float s = 0.f;
            for (int d = tid; d < D_; d += 256) { float v = c[d]; s += v * v; }
            s = block_sum_bcast(s, sred, tid);
            float rn = 1.0f / sqrtf(s);
            float s2 = 0.f;
            for (int d = tid; d < D_; d += 256) {
                float v = c[d] * rn;
                cnbf[(size_t)p * D_ + d] = f2bf(v);
                s2 += v * v;
            }
            s2 = block_sum_bcast(s2, sred, tid);
            if (tid == 0) csq[p] = s2;
        } else {
            for (int d = tid; d < D_; d += 256) cnbf[(size_t)p * D_ + d] = 0;
            if (tid == 0) csq[p] = 1e30f;
        }
    }
}

// ---------------------------------------------------------------------------
// MFMA tile kernel: 128x128 output tile per block, m97 structure.
// grid = (NJT+1, N_/128). jt<NJT: X.X^T tile; jt==NJT: X.cn^T (128 padded centers).
__global__ __launch_bounds__(256) void mfma_kernel(
    const unsigned short* __restrict__ Xbf, const unsigned short* __restrict__ cnbf,
    const int* __restrict__ T, const float* __restrict__ sq,
    const float* __restrict__ csq,
    float* __restrict__ ap_part, float* __restrict__ an_part,
    float* __restrict__ minc) {
    __shared__ __align__(16) unsigned short As[128 * 32];
    __shared__ __align__(16) unsigned short Bs[128 * 32];

    const int tid = threadIdx.x;
    const int l = tid & 63;
    const int w = tid >> 6;       // wave 0..3
    const int wr = w >> 1;        // wave row (0/1) -> 64 rows
    const int wc = w & 1;         // wave col (0/1) -> 64 cols
    const int it = blockIdx.y;
    const int jt = blockIdx.x;
    const bool is_center = (jt == NJT);
    const int i0 = it * 128;
    const int j0 = is_center ? 0 : jt * 128;
    const unsigned short* __restrict__ Bmat = is_center ? cnbf : Xbf;

    const int srow = l >> 2;      // 0..15: row within 16-row staging chunk
    const int skc = (l & 3) * 8;  // 0,8,16,24: k element offset (16B)

    f32x4 acc[4][4];
#pragma unroll
    for (int m = 0; m < 4; ++m)
#pragma unroll
        for (int n = 0; n < 4; ++n) acc[m][n] = (f32x4){0.f, 0.f, 0.f, 0.f};

    const int col = l & 15;
    const int hi = l >> 4;

    for (int kt = 0; kt < D_ / 32; ++kt) {
        const int k0 = kt * 32;
        // stage A (8KB) + B (8KB): wave w handles 16-row chunks w and w+4
        {
            const unsigned short* ga0 = Xbf + (size_t)(i0 + w * 16 + srow) * D_ + k0 + skc;
            const unsigned short* ga1 = Xbf + (size_t)(i0 + (w + 4) * 16 + srow) * D_ + k0 + skc;
            const unsigned short* gb0 = Bmat + (size_t)(j0 + w * 16 + srow) * D_ + k0 + skc;
            const unsigned short* gb1 = Bmat + (size_t)(j0 + (w + 4) * 16 + srow) * D_ + k0 + skc;
            GLOAD16(ga0, &As[w * 512]);
            GLOAD16(ga1, &As[(w + 4) * 512]);
            GLOAD16(gb0, &Bs[w * 512]);
            GLOAD16(gb1, &Bs[(w + 4) * 512]);
        }
        __syncthreads();  // compiler drains vmcnt before barrier

        short8 a[4], b[4];
#pragma unroll
        for (int m = 0; m < 4; ++m)
            a[m] = *reinterpret_cast<const short8*>(&As[(wr * 64 + m * 16 + col) * 32 + hi * 8]);
#pragma unroll
        for (int n = 0; n < 4; ++n)
            b[n] = *reinterpret_cast<const short8*>(&Bs[(wc * 64 + n * 16 + col) * 32 + hi * 8]);
#pragma unroll
        for (int m = 0; m < 4; ++m)
#pragma unroll
            for (int n = 0; n < 4; ++n)
                acc[m][n] = __builtin_amdgcn_mfma_f32_16x16x32_bf16(a[m], b[n], acc[m][n], 0, 0, 0);
        __syncthreads();  // reads done before next stage overwrites
    }

    // ---------------- epilogue: fused distance + hardest pos/neg ----------
    // C/D layout: col = lane&15, row = (lane>>4)*4 + reg  [m89/m91 verified]
    if (!is_center) {
        float sqj[4]; int tj[4];
#pragma unroll
        for (int n = 0; n < 4; ++n) {
            int j = j0 + wc * 64 + n * 16 + col;
            sqj[n] = sq[j];
            tj[n] = T[j];
        }
#pragma unroll
        for (int m = 0; m < 4; ++m) {
#pragma unroll
            for (int r = 0; r < 4; ++r) {
                int i = i0 + wr * 64 + m * 16 + hi * 4 + r;
                float sqi = sq[i];
                int ti = T[i];
                float ap = -1e30f, an = 1e30f;
#pragma unroll
                for (int n = 0; n < 4; ++n) {
                    float d2 = sqi + sqj[n] - 2.0f * acc[m][n][r];
                    float d = sqrtf(fmaxf(d2, 1e-12f));
                    if (tj[n] == ti) ap = fmaxf(ap, d);
                    else an = fminf(an, d);
                }
#pragma unroll
                for (int msk = 1; msk < 16; msk <<= 1) {
                    ap = fmaxf(ap, __shfl_xor(ap, msk));
                    an = fminf(an, __shfl_xor(an, msk));
                }
                if (col == 0) {
                    ap_part[(size_t)(jt * 2 + wc) * N_ + i] = ap;
                    an_part[(size_t)(jt * 2 + wc) * N_ + i] = an;
                }
            }
        }
    } else {
        float sqj[4];
#pragma unroll
        for (int n = 0; n < 4; ++n) sqj[n] = csq[wc * 64 + n * 16 + col];
#pragma unroll
        for (int m = 0; m < 4; ++m) {
#pragma unroll
            for (int r = 0; r < 4; ++r) {
                int i = i0 + wr * 64 + m * 16 + hi * 4 + r;
                float sqi = sq[i];
                float mc = 1e30f;
#pragma unroll
                for (int n = 0; n < 4; ++n) {
                    float d2 = sqi + sqj[n] - 2.0f * acc[m][n][r];
                    float d = fmaxf(sqrtf(fmaxf(d2, 0.0f)), 1e-12f);
                    mc = fminf(mc, d);
                }
#pragma unroll
                for (int msk = 1; msk < 16; msk <<= 1)
                    mc = fminf(mc, __shfl_xor(mc, msk));
                if (col == 0) minc[(size_t)wc * N_ + i] = mc;
            }
        }
    }
}

// ---------------------------------------------------------------------------
// combine: fold 64 partial slots per row + center min, per-row loss term,
// block-sum into bsum[16]
__global__ __launch_bounds__(256) void combine1(
    const float* __restrict__ ap_part, const float* __restrict__ an_part,
    const float* __restrict__ minc, float* __restrict__ bsum) {
    __shared__ float sred[4];
    int i = blockIdx.x * 256 + threadIdx.x;
    float ap = -1e30f, an = 1e30f;
#pragma unroll 8
    for (int s = 0; s < NSLOT; ++s) {
        ap = fmaxf(ap, ap_part[(size_t)s * N_ + i]);
        an = fminf(an, an_part[(size_t)s * N_ + i]);
    }
    float dan = (an < 1e29f) ? an : (ap + 1.0f);
    dan = fminf(dan, fminf(minc[i], minc[N_ + i]));
    float term = fmaxf(0.0f, 1.0f + ap - dan);
    term = block_sum_bcast(term, sred, threadIdx.x);
    if (threadIdx.x == 0) bsum[blockIdx.x] = term;
}

__global__ void finalize(const float* __restrict__ bsum, float* __restrict__ out) {
    if (threadIdx.x == 0) {
        float s = 0.f;
        for (int b = 0; b < N_ / 256; ++b) s += bsum[b];
        out[0] = s / (float)N_;
    }
}

// ---------------------------------------------------------------------------
extern "C" void kernel_launch(void* const* d_in, const int* in_sizes, int n_in,
                              void* d_out, int out_size, void* d_ws, size_t ws_size,
                              hipStream_t stream) {
    const float* X = (const float*)d_in[0];
    const int* T = (const int*)d_in[1];
    const float* C = (const float*)d_in[2];
    float* out = (float*)d_out;

    float* ws = (float*)d_ws;
    float* sq = ws;                            // 4096
    float* csq = ws + 4096;                    // 128
    float* minc = ws + 4224;                   // 2*4096 = 8192
    float* bsum = ws + 12416;                  // 16 (+16 pad)
    unsigned short* Xbf = (unsigned short*)(ws + 12448);   // 4096*768 us = 1,572,864 fl
    unsigned short* cnbf = (unsigned short*)(ws + 1585312);// 128*768 us = 49,152 fl
    float* ap_part = ws + 1634464;             // 64*4096 = 262,144
    float* an_part = ws + 1896608;             // 262,144 (end 2,158,752 fl ≈ 8.24 MB)

    pre_kernel<<<N_ + PPAD, 256, 0, stream>>>(X, C, sq, Xbf, cnbf, csq);
    dim3 grid(NJT + 1, N_ / 128);
    mfma_kernel<<<grid, 256, 0, stream>>>(Xbf, cnbf, T, sq, csq, ap_part, an_part, minc);
    combine1<<<N_ / 256, 256, 0, stream>>>(ap_part, an_part, minc, bsum);
    finalize<<<1, 64, 0, stream>>>(bsum, out);
}

// Round 3
// 69.399 us; speedup vs baseline: 8.3586x; 1.3099x over previous
//
#include <hip/hip_runtime.h>
#include <math.h>

#define N_ 4096
#define D_ 768
#define P_ 100
#define PPAD 128
#define NJT 32                  /* j-tiles over X (128 each); jt==32 -> centers */
#define NSLOT (NJT * 2)         /* 64 partial slots (2 wave-cols per block) */
#define NT 24                   /* K-tiles: 768 / 32 */

typedef __attribute__((ext_vector_type(8))) short short8;
typedef __attribute__((ext_vector_type(4))) float f32x4;

typedef const __attribute__((address_space(1))) void* gld_src_t;
typedef __attribute__((address_space(3))) void* gld_dst_t;
#define GLOAD16(g, d) __builtin_amdgcn_global_load_lds((gld_src_t)(g), (gld_dst_t)(d), 16, 0, 0)

#define WAITVM4() asm volatile("s_waitcnt vmcnt(4)" ::: "memory")
#define WAITVM0() asm volatile("s_waitcnt vmcnt(0)" ::: "memory")
static __device__ __forceinline__ void barrier_fenced() {
    asm volatile("" ::: "memory");
    __builtin_amdgcn_s_barrier();
    asm volatile("" ::: "memory");
}

// float -> bf16 (RNE)
__device__ inline unsigned short f2bf(float f) {
    union { float f; unsigned int u; } v; v.f = f;
    unsigned int u = v.u + 0x7fffu + ((v.u >> 16) & 1u);
    return (unsigned short)(u >> 16);
}

// ---------------------------------------------------------------------------
// pre: one wave per row. sq[i]=||x_i||^2 fp32; Xbf=bf16(X); cnbf=bf16(row-
// normalized C, padded to 128 rows of zeros); csq fp32 (1e30 for pads).
__global__ __launch_bounds__(256) void pre_kernel(
    const float* __restrict__ X, const float* __restrict__ C,
    float* __restrict__ sq, unsigned short* __restrict__ Xbf,
    unsigned short* __restrict__ cnbf, float* __restrict__ csq) {
    const int gw = blockIdx.x * 4 + (threadIdx.x >> 6);
    const int l = threadIdx.x & 63;
    if (gw < N_) {
        const float4* x4 = (const float4*)(X + (size_t)gw * D_);
        short4* ob = (short4*)(Xbf + (size_t)gw * D_);
        float s = 0.f;
#pragma unroll
        for (int c = 0; c < 3; ++c) {
            float4 v = x4[c * 64 + l];
            s = fmaf(v.x, v.x, fmaf(v.y, v.y, fmaf(v.z, v.z, fmaf(v.w, v.w, s))));
            short4 o;
            o.x = (short)f2bf(v.x); o.y = (short)f2bf(v.y);
            o.z = (short)f2bf(v.z); o.w = (short)f2bf(v.w);
            ob[c * 64 + l] = o;
        }
#pragma unroll
        for (int m = 1; m < 64; m <<= 1) s += __shfl_xor(s, m);
        if (l == 0) sq[gw] = s;
    } else {
        const int p = gw - N_;
        if (p >= PPAD) return;
        short4* ob = (short4*)(cnbf + (size_t)p * D_);
        if (p < P_) {
            const float4* c4 = (const float4*)(C + (size_t)p * D_);
            float4 v[3];
            float s = 0.f;
#pragma unroll
            for (int c = 0; c < 3; ++c) {
                v[c] = c4[c * 64 + l];
                s = fmaf(v[c].x, v[c].x, fmaf(v[c].y, v[c].y,
                    fmaf(v[c].z, v[c].z, fmaf(v[c].w, v[c].w, s))));
            }
#pragma unroll
            for (int m = 1; m < 64; m <<= 1) s += __shfl_xor(s, m);
            float rn = 1.0f / sqrtf(s);
#pragma unroll
            for (int c = 0; c < 3; ++c) {
                short4 o;
                o.x = (short)f2bf(v[c].x * rn); o.y = (short)f2bf(v[c].y * rn);
                o.z = (short)f2bf(v[c].z * rn); o.w = (short)f2bf(v[c].w * rn);
                ob[c * 64 + l] = o;
            }
            if (l == 0) csq[p] = s * rn * rn;
        } else {
            short4 z; z.x = z.y = z.z = z.w = 0;
#pragma unroll
            for (int c = 0; c < 3; ++c) ob[c * 64 + l] = z;
            if (l == 0) csq[p] = 1e30f;
        }
    }
}

// ---------------------------------------------------------------------------
// MFMA kernel: 128x128 tile, BK=32, 3-buffer LDS ring, counted vmcnt,
// raw barriers, XOR-swizzled LDS (flip = ((row&6)>>1)<<4 bytes).
__global__ __launch_bounds__(256, 3) void mfma_kernel(
    const unsigned short* __restrict__ Xbf, const unsigned short* __restrict__ cnbf,
    const int* __restrict__ T, const float* __restrict__ sq,
    const float* __restrict__ csq,
    float* __restrict__ ap_part, float* __restrict__ an_part,
    float* __restrict__ minc) {
    // 3 buffers x (A 4096 us + B 4096 us) = 48 KB
    __shared__ __align__(16) unsigned short lds[3 * 8192];

    const int tid = threadIdx.x;
    const int l = tid & 63;
    const int w = tid >> 6;       // wave 0..3
    const int wr = w >> 1;        // wave row (0/1) -> 64 rows
    const int wc = w & 1;         // wave col (0/1) -> 64 cols

    // bijective XCD swizzle: 1056 blocks = 8 * 132
    const int orig = blockIdx.y * 33 + blockIdx.x;
    const int wg = (orig & 7) * 132 + (orig >> 3);
    const int it = wg / 33;
    const int jt = wg % 33;
    const bool is_center = (jt == NJT);
    const int i0 = it * 128;
    const int j0 = is_center ? 0 : jt * 128;
    const unsigned short* __restrict__ Bmat = is_center ? cnbf : Xbf;

    // ---- staging addressing (per thread) ----
    // dest linear ushort off (per j-chunk): tid*8 + j*2048 -> row=tid>>2 (+j*64),
    // dest col_us=(tid&3)*8. source col pre-swizzled by flip(row).
    const int srow = tid >> 2;                                  // 0..63
    const int scol = ((tid & 3) * 8) ^ (((srow & 6) >> 1) << 3);
    const unsigned short* gA0 = Xbf + (size_t)(i0 + srow) * D_ + scol;
    const unsigned short* gA1 = gA0 + (size_t)64 * D_;
    const unsigned short* gB0 = Bmat + (size_t)(j0 + srow) * D_ + scol;
    const unsigned short* gB1 = gB0 + (size_t)64 * D_;
    const int dA0 = w * 512, dA1 = 2048 + w * 512;
    const int dB0 = 4096 + w * 512, dB1 = 6144 + w * 512;

    // ---- fragment read addressing (swizzled) ----
    const int col = l & 15;
    const int hi = l >> 4;
    const int rko = (hi * 8) ^ ((l & 6) << 2);                  // k ushort off ^ flip
    const int aro = (wr * 64 + col) * 32 + rko;                 // + m*512
    const int bro = 4096 + (wc * 64 + col) * 32 + rko;          // + n*512

    f32x4 acc[4][4];
#pragma unroll
    for (int m = 0; m < 4; ++m)
#pragma unroll
        for (int n = 0; n < 4; ++n) acc[m][n] = (f32x4){0.f, 0.f, 0.f, 0.f};

#define STAGE(t)                                                     \
    do {                                                             \
        const int bo_ = ((t) % 3) * 8192;                            \
        const int ke_ = (t) * 32;                                    \
        GLOAD16(gA0 + ke_, &lds[bo_ + dA0]);                         \
        GLOAD16(gA1 + ke_, &lds[bo_ + dA1]);                         \
        GLOAD16(gB0 + ke_, &lds[bo_ + dB0]);                         \
        GLOAD16(gB1 + ke_, &lds[bo_ + dB1]);                         \
    } while (0)

    STAGE(0);
    STAGE(1);
    WAITVM4();               // K-tile 0 landed (K-tile 1's 4 loads in flight)
    barrier_fenced();

    int bo = 0;
    for (int t = 0; t < NT; ++t) {
        if (t + 2 < NT) STAGE(t + 2);   // ring slot (t+2)%3 was freed at t-1
        const unsigned short* Lb = &lds[bo * 8192];
        short8 a[4], b[4];
#pragma unroll
        for (int m = 0; m < 4; ++m)
            a[m] = *reinterpret_cast<const short8*>(Lb + aro + m * 512);
#pragma unroll
        for (int n = 0; n < 4; ++n)
            b[n] = *reinterpret_cast<const short8*>(Lb + bro + n * 512);
        __builtin_amdgcn_s_setprio(1);
#pragma unroll
        for (int m = 0; m < 4; ++m)
#pragma unroll
            for (int n = 0; n < 4; ++n)
                acc[m][n] = __builtin_amdgcn_mfma_f32_16x16x32_bf16(a[m], b[n], acc[m][n], 0, 0, 0);
        __builtin_amdgcn_s_setprio(0);
        if (t < NT - 1) {
            if (t + 2 < NT) WAITVM4();  // next tile landed; keep 4 in flight
            else WAITVM0();             // pipeline drain at the tail
            barrier_fenced();
        }
        bo = (bo == 2) ? 0 : bo + 1;
    }
#undef STAGE

    // ---------------- epilogue (loads only AFTER the counted-vmcnt loop) ----
    // C/D layout: col = lane&15, row = (lane>>4)*4 + reg
    if (!is_center) {
        float sqj[4]; int tj[4];
#pragma unroll
        for (int n = 0; n < 4; ++n) {
            int j = j0 + wc * 64 + n * 16 + col;
            sqj[n] = sq[j];
            tj[n] = T[j];
        }
#pragma unroll
        for (int m = 0; m < 4; ++m) {
#pragma unroll
            for (int r = 0; r < 4; ++r) {
                int i = i0 + wr * 64 + m * 16 + hi * 4 + r;
                float sqi = sq[i];
                int ti = T[i];
                float ap = -1e30f, an = 1e30f;
#pragma unroll
                for (int n = 0; n < 4; ++n) {
                    float d2 = sqi + sqj[n] - 2.0f * acc[m][n][r];
                    float d = sqrtf(fmaxf(d2, 1e-12f));
                    if (tj[n] == ti) ap = fmaxf(ap, d);
                    else an = fminf(an, d);
                }
#pragma unroll
                for (int msk = 1; msk < 16; msk <<= 1) {
                    ap = fmaxf(ap, __shfl_xor(ap, msk));
                    an = fminf(an, __shfl_xor(an, msk));
                }
                if (col == 0) {
                    ap_part[(size_t)(jt * 2 + wc) * N_ + i] = ap;
                    an_part[(size_t)(jt * 2 + wc) * N_ + i] = an;
                }
            }
        }
    } else {
        float sqj[4];
#pragma unroll
        for (int n = 0; n < 4; ++n) sqj[n] = csq[wc * 64 + n * 16 + col];
#pragma unroll
        for (int m = 0; m < 4; ++m) {
#pragma unroll
            for (int r = 0; r < 4; ++r) {
                int i = i0 + wr * 64 + m * 16 + hi * 4 + r;
                float sqi = sq[i];
                float mc = 1e30f;
#pragma unroll
                for (int n = 0; n < 4; ++n) {
                    float d2 = sqi + sqj[n] - 2.0f * acc[m][n][r];
                    float d = fmaxf(sqrtf(fmaxf(d2, 0.0f)), 1e-12f);
                    mc = fminf(mc, d);
                }
#pragma unroll
                for (int msk = 1; msk < 16; msk <<= 1)
                    mc = fminf(mc, __shfl_xor(mc, msk));
                if (col == 0) minc[(size_t)wc * N_ + i] = mc;
            }
        }
    }
}

// ---------------------------------------------------------------------------
__device__ inline float block_sum_bcast(float v, float* sred, int tid) {
#pragma unroll
    for (int m = 32; m > 0; m >>= 1) v += __shfl_xor(v, m);
    if ((tid & 63) == 0) sred[tid >> 6] = v;
    __syncthreads();
    float r = sred[0] + sred[1] + sred[2] + sred[3];
    __syncthreads();
    return r;
}

__global__ __launch_bounds__(256) void combine1(
    const float* __restrict__ ap_part, const float* __restrict__ an_part,
    const float* __restrict__ minc, float* __restrict__ bsum) {
    __shared__ float sred[4];
    int i = blockIdx.x * 256 + threadIdx.x;
    float ap = -1e30f, an = 1e30f;
#pragma unroll 8
    for (int s = 0; s < NSLOT; ++s) {
        ap = fmaxf(ap, ap_part[(size_t)s * N_ + i]);
        an = fminf(an, an_part[(size_t)s * N_ + i]);
    }
    float dan = (an < 1e29f) ? an : (ap + 1.0f);
    dan = fminf(dan, fminf(minc[i], minc[N_ + i]));
    float term = fmaxf(0.0f, 1.0f + ap - dan);
    term = block_sum_bcast(term, sred, threadIdx.x);
    if (threadIdx.x == 0) bsum[blockIdx.x] = term;
}

__global__ void finalize(const float* __restrict__ bsum, float* __restrict__ out) {
    if (threadIdx.x == 0) {
        float s = 0.f;
        for (int b = 0; b < N_ / 256; ++b) s += bsum[b];
        out[0] = s / (float)N_;
    }
}

// ---------------------------------------------------------------------------
extern "C" void kernel_launch(void* const* d_in, const int* in_sizes, int n_in,
                              void* d_out, int out_size, void* d_ws, size_t ws_size,
                              hipStream_t stream) {
    const float* X = (const float*)d_in[0];
    const int* T = (const int*)d_in[1];
    const float* C = (const float*)d_in[2];
    float* out = (float*)d_out;

    float* ws = (float*)d_ws;
    float* sq = ws;                            // 4096
    float* csq = ws + 4096;                    // 128
    float* minc = ws + 4224;                   // 2*4096 = 8192
    float* bsum = ws + 12416;                  // 16 (+16 pad)
    unsigned short* Xbf = (unsigned short*)(ws + 12448);    // 4096*768 us
    unsigned short* cnbf = (unsigned short*)(ws + 1585312); // 128*768 us
    float* ap_part = ws + 1634464;             // 64*4096
    float* an_part = ws + 1896608;             // 64*4096 (end ~8.24 MB)

    pre_kernel<<<(N_ + PPAD) / 4, 256, 0, stream>>>(X, C, sq, Xbf, cnbf, csq);
    dim3 grid(33, 32);
    mfma_kernel<<<grid, 256, 0, stream>>>(Xbf, cnbf, T, sq, csq, ap_part, an_part, minc);
    combine1<<<N_ / 256, 256, 0, stream>>>(ap_part, an_part, minc, bsum);
    finalize<<<1, 64, 0, stream>>>(bsum, out);
}

// Round 4
// 66.183 us; speedup vs baseline: 8.7648x; 1.0486x over previous
//
#include <hip/hip_runtime.h>
#include <math.h>

#define N_ 4096
#define D_ 768
#define P_ 100
#define NROWS 4352              /* X 4096 + cn 100 + pad 156 */
#define NT 12                   /* K-tiles: 768 / 64 */
#define NIT 16                  /* 256-row i-tiles */
#define NTRI 136                /* lower-tri incl diag */
#define NBLK 152                /* 136 + 16 center tiles */

typedef __attribute__((ext_vector_type(8))) short short8;
typedef __attribute__((ext_vector_type(4))) float f32x4;

typedef const __attribute__((address_space(1))) void* gld_src_t;
typedef __attribute__((address_space(3))) void* gld_dst_t;
#define GLOAD16(g, d) __builtin_amdgcn_global_load_lds((gld_src_t)(g), (gld_dst_t)(d), 16, 0, 0)

// float -> bf16 (RNE)
__device__ inline unsigned short f2bf(float f) {
    union { float f; unsigned int u; } v; v.f = f;
    unsigned int u = v.u + 0x7fffu + ((v.u >> 16) & 1u);
    return (unsigned short)(u >> 16);
}

// ---------------------------------------------------------------------------
// pre: one wave per row of concatenated [X; normalized C; zero-pad].
// sqc[r] = ||row||^2 (1e30 for pads), XC = bf16 rows.
__global__ __launch_bounds__(256) void pre_kernel(
    const float* __restrict__ X, const float* __restrict__ C,
    float* __restrict__ sqc, unsigned short* __restrict__ XC) {
    const int gw = blockIdx.x * 4 + (threadIdx.x >> 6);
    const int l = threadIdx.x & 63;
    short4* ob = (short4*)(XC + (size_t)gw * D_);
    if (gw < N_) {
        const float4* x4 = (const float4*)(X + (size_t)gw * D_);
        float s = 0.f;
#pragma unroll
        for (int c = 0; c < 3; ++c) {
            float4 v = x4[c * 64 + l];
            s = fmaf(v.x, v.x, fmaf(v.y, v.y, fmaf(v.z, v.z, fmaf(v.w, v.w, s))));
            short4 o;
            o.x = (short)f2bf(v.x); o.y = (short)f2bf(v.y);
            o.z = (short)f2bf(v.z); o.w = (short)f2bf(v.w);
            ob[c * 64 + l] = o;
        }
#pragma unroll
        for (int m = 1; m < 64; m <<= 1) s += __shfl_xor(s, m);
        if (l == 0) sqc[gw] = s;
    } else {
        const int p = gw - N_;
        if (p < P_) {
            const float4* c4 = (const float4*)(C + (size_t)p * D_);
            float4 v[3];
            float s = 0.f;
#pragma unroll
            for (int c = 0; c < 3; ++c) {
                v[c] = c4[c * 64 + l];
                s = fmaf(v[c].x, v[c].x, fmaf(v[c].y, v[c].y,
                    fmaf(v[c].z, v[c].z, fmaf(v[c].w, v[c].w, s))));
            }
#pragma unroll
            for (int m = 1; m < 64; m <<= 1) s += __shfl_xor(s, m);
            float rn = 1.0f / sqrtf(s);
#pragma unroll
            for (int c = 0; c < 3; ++c) {
                short4 o;
                o.x = (short)f2bf(v[c].x * rn); o.y = (short)f2bf(v[c].y * rn);
                o.z = (short)f2bf(v[c].z * rn); o.w = (short)f2bf(v[c].w * rn);
                ob[c * 64 + l] = o;
            }
            if (l == 0) sqc[gw] = s * rn * rn;
        } else {
            short4 z; z.x = z.y = z.z = z.w = 0;
#pragma unroll
            for (int c = 0; c < 3; ++c) ob[c * 64 + l] = z;
            if (l == 0) sqc[gw] = 1e30f;
        }
    }
}

// ---------------------------------------------------------------------------
// 256x256 tile, BK=64, 8 waves (2M x 4N), 4 phases per K-tile, counted vmcnt.
// Symmetric: lower-tri tiles feed row-side AND col-side reductions.
// LDS: 8 regions x 16KB: [buf][mat A/B][k-half], each 256 rows x 32 us (64B).
__global__ __launch_bounds__(512, 2) void mfma256(
    const unsigned short* __restrict__ XC, const int* __restrict__ T,
    const float* __restrict__ sqc,
    float* __restrict__ ap_part, float* __restrict__ an_part,
    float* __restrict__ minc) {
    __shared__ __align__(16) unsigned short lds[65536];   // 128 KB

    const int tid = threadIdx.x;
    const int l = tid & 63;
    const int w = tid >> 6;          // 0..7
    const int wm = w >> 2;           // 0/1 -> 128-row half
    const int wn = w & 3;            // 0..3 -> 64-col strip
    const int col = l & 15;
    const int hi = l >> 4;

    // XCD swizzle (152 = 8*19, bijective) then triangular decode
    const int bid0 = blockIdx.x;
    const int bid = (bid0 & 7) * 19 + (bid0 >> 3);
    int it, jt;
    if (bid < NTRI) {
        int t = (int)((sqrtf(8.0f * bid + 1.0f) - 1.0f) * 0.5f);
        t += ((t + 1) * (t + 2) / 2 <= bid);
        t -= (t * (t + 1) / 2 > bid);
        it = t; jt = bid - t * (t + 1) / 2;
    } else { it = bid - NTRI; jt = 16; }
    const int i0 = it * 256, j0 = jt * 256;
    const bool is_center = (jt == 16);

    // ---- staging: per thread 16B x2 per (mat, k-half); linear LDS dest,
    // pre-swizzled global source column (verified zero-conflict pattern) ----
    const int srow = tid >> 2;                               // 0..127
    const int scol = ((tid & 3) * 8) ^ ((srow & 6) << 2);    // ushorts
    const unsigned short* gA = XC + (size_t)(i0 + srow) * D_ + scol;
    const unsigned short* gB = XC + (size_t)(j0 + srow) * D_ + scol;
    const int dof = tid * 8;                                 // us

#define REGOFF(c, mat, ks) (((c) * 4 + (mat) * 2 + (ks)) * 8192)

#define STAGE2(MAT, TT, KS)                                              \
    do {                                                                 \
        unsigned short* d_ = lds + REGOFF((TT) & 1, MAT, KS) + dof;      \
        const unsigned short* s_ = ((MAT) ? gB : gA) + (TT) * 64 + (KS) * 32; \
        GLOAD16(s_, d_);                                                 \
        GLOAD16(s_ + (size_t)128 * D_, d_ + 4096);                       \
    } while (0)

    // ---- fragment read addressing (swizzled, matches stage flip) ----
    const int rko = (hi * 8) ^ ((l & 6) << 2);

    f32x4 acc[8][4];
#pragma unroll
    for (int m = 0; m < 8; ++m)
#pragma unroll
        for (int n = 0; n < 4; ++n) acc[m][n] = (f32x4){0.f, 0.f, 0.f, 0.f};

    short8 afr[4], bfr[4];

    // Phase: read frags -> optional stage -> barrier -> lgkm0 -> 16 MFMA ->
    // optional counted vmcnt -> barrier.  WVM: -1 none, else immediate.
#define PHASE(MH, KS, DOSTAGE, SMAT, STILE, SKS, WVM)                        \
    do {                                                                     \
        const unsigned short* Ab_ = lds + REGOFF(cbuf, 0, KS);               \
        const unsigned short* Bb_ = lds + REGOFF(cbuf, 1, KS);               \
        if (MH == 0) {                                                       \
            _Pragma("unroll") for (int n = 0; n < 4; ++n)                    \
                bfr[n] = *(const short8*)(Bb_ + (wn * 64 + n * 16 + col) * 32 + rko); \
        }                                                                    \
        _Pragma("unroll") for (int q = 0; q < 4; ++q)                        \
            afr[q] = *(const short8*)(Ab_ + (wm * 128 + ((MH) * 4 + q) * 16 + col) * 32 + rko); \
        if (DOSTAGE) STAGE2(SMAT, STILE, SKS);                               \
        __builtin_amdgcn_s_barrier();                                        \
        asm volatile("s_waitcnt lgkmcnt(0)" ::: "memory");                   \
        __builtin_amdgcn_sched_barrier(0);                                   \
        __builtin_amdgcn_s_setprio(1);                                       \
        _Pragma("unroll") for (int q = 0; q < 4; ++q)                        \
            _Pragma("unroll") for (int n = 0; n < 4; ++n)                    \
                acc[(MH) * 4 + q][n] = __builtin_amdgcn_mfma_f32_16x16x32_bf16( \
                    afr[q], bfr[n], acc[(MH) * 4 + q][n], 0, 0, 0);          \
        __builtin_amdgcn_s_setprio(0);                                       \
        if ((WVM) == 8) asm volatile("s_waitcnt vmcnt(8)" ::: "memory");     \
        else if ((WVM) == 4) asm volatile("s_waitcnt vmcnt(4)" ::: "memory");\
        else if ((WVM) == 0) asm volatile("s_waitcnt vmcnt(0)" ::: "memory");\
        __builtin_amdgcn_s_barrier();                                        \
        __builtin_amdgcn_sched_barrier(0);                                   \
    } while (0)

    // prologue: t0 full + t1 ks0  (12 loads/thread); land t0ks0 (keep 8 in flight)
    STAGE2(0, 0, 0); STAGE2(1, 0, 0);
    STAGE2(0, 0, 1); STAGE2(1, 0, 1);
    STAGE2(0, 1, 0); STAGE2(1, 1, 0);
    asm volatile("s_waitcnt vmcnt(8)" ::: "memory");
    __builtin_amdgcn_s_barrier();
    __builtin_amdgcn_sched_barrier(0);

    // steady: iter t stages (t+1)ks1 in ph1-2, (t+2)ks0 in ph3-4; vmcnt(8)
    // at ph2/ph4 keeps 8 loads (2 k-half-regions) in flight.
    for (int t = 0; t < 10; ++t) {
        const int cbuf = t & 1;
        PHASE(0, 0, true, 0, t + 1, 1, -1);
        PHASE(1, 0, true, 1, t + 1, 1, 8);
        PHASE(0, 1, true, 0, t + 2, 0, -1);
        PHASE(1, 1, true, 1, t + 2, 0, 8);
    }
    {   // t = 10: no (t+2) stage; drain to 4 (tile 11 ks1 still in flight)
        const int cbuf = 0;
        PHASE(0, 0, true, 0, 11, 1, -1);
        PHASE(1, 0, true, 1, 11, 1, 8);
        PHASE(0, 1, false, 0, 0, 0, -1);
        PHASE(1, 1, false, 0, 0, 0, 4);
    }
    {   // t = 11: full drain before ks1 phases
        const int cbuf = 1;
        PHASE(0, 0, false, 0, 0, 0, -1);
        PHASE(1, 0, false, 0, 0, 0, 0);
        PHASE(0, 1, false, 0, 0, 0, -1);
        PHASE(1, 1, false, 0, 0, 0, -1);
    }
#undef PHASE
#undef STAGE2

    // ---------------- epilogue: fused distances + dual-side reductions ----
    // C/D layout: col = lane&15, row = (lane>>4)*4 + reg
    float sqj[4]; int tj[4];
#pragma unroll
    for (int n = 0; n < 4; ++n) {
        int j = j0 + wn * 64 + n * 16 + col;
        sqj[n] = sqc[j];
        tj[n] = is_center ? -1 : T[j];
    }
    float apC[4], anC[4];
#pragma unroll
    for (int n = 0; n < 4; ++n) { apC[n] = -1e30f; anC[n] = 1e30f; }

    float* lf = (float*)lds;   // reuse LDS: [0..1023]=ap by wn, [1024..2047]=an

#pragma unroll
    for (int m = 0; m < 8; ++m) {
#pragma unroll
        for (int r = 0; r < 4; ++r) {
            const int lrow = wm * 128 + m * 16 + hi * 4 + r;   // 0..255
            const int i = i0 + lrow;
            const float sqi = sqc[i];
            const int ti = T[i];
            float apR = -1e30f, anR = 1e30f;
#pragma unroll
            for (int n = 0; n < 4; ++n) {
                float d2 = sqi + sqj[n] - 2.0f * acc[m][n][r];
                if (is_center) {
                    float dc = fmaxf(sqrtf(fmaxf(d2, 0.0f)), 1e-12f);
                    apR = fminf(apR == -1e30f ? 1e30f : apR, dc);  // min-center
                    if (n == 0) apR = dc;                          // init clean
                    else apR = fminf(apR, dc);
                } else {
                    float d = sqrtf(fmaxf(d2, 1e-12f));
                    bool same = (tj[n] == ti);
                    apR = same ? fmaxf(apR, d) : apR;
                    anR = same ? anR : fminf(anR, d);
                    apC[n] = same ? fmaxf(apC[n], d) : apC[n];
                    anC[n] = same ? anC[n] : fminf(anC[n], d);
                }
            }
            // row-side reduce across the 16 col-lanes
#pragma unroll
            for (int msk = 1; msk < 16; msk <<= 1) {
                if (is_center) apR = fminf(apR, __shfl_xor(apR, msk));
                else {
                    apR = fmaxf(apR, __shfl_xor(apR, msk));
                    anR = fminf(anR, __shfl_xor(anR, msk));
                }
            }
            if (col == 0) {
                lf[wn * 256 + lrow] = apR;
                if (!is_center) lf[1024 + wn * 256 + lrow] = anR;
            }
        }
    }
    __syncthreads();
    // fold across the 4 wn-waves, store one slot per tile-side
    if (tid < 256) {
        float a0 = lf[tid], a1 = lf[256 + tid], a2 = lf[512 + tid], a3 = lf[768 + tid];
        int i = i0 + tid;
        if (is_center) {
            minc[i] = fminf(fminf(a0, a1), fminf(a2, a3));
        } else {
            ap_part[(size_t)jt * N_ + i] = fmaxf(fmaxf(a0, a1), fmaxf(a2, a3));
            float b0 = lf[1024 + tid], b1 = lf[1280 + tid],
                  b2 = lf[1536 + tid], b3 = lf[1792 + tid];
            an_part[(size_t)jt * N_ + i] = fminf(fminf(b0, b1), fminf(b2, b3));
        }
    }

    // col side (off-diagonal, non-center tiles only)
    if (!is_center && it != jt) {
        __syncthreads();
#pragma unroll
        for (int n = 0; n < 4; ++n) {
#pragma unroll
            for (int msk = 16; msk < 64; msk <<= 1) {
                apC[n] = fmaxf(apC[n], __shfl_xor(apC[n], msk));
                anC[n] = fminf(anC[n], __shfl_xor(anC[n], msk));
            }
            if (hi == 0) {
                int lcol = wn * 64 + n * 16 + col;             // 0..255
                lf[wm * 256 + lcol] = apC[n];
                lf[1024 + wm * 256 + lcol] = anC[n];
                if (wm == 0) { lf[512 + lcol] = -1e30f; }      // unused halves
            }
        }
        __syncthreads();
        if (tid < 256) {
            float a0 = lf[tid], a1 = lf[256 + tid];
            float b0 = lf[1024 + tid], b1 = lf[1280 + tid];
            int j = j0 + tid;
            ap_part[(size_t)(16 + it) * N_ + j] = fmaxf(a0, a1);
            an_part[(size_t)(16 + it) * N_ + j] = fminf(b0, b1);
        }
    }
}

// ---------------------------------------------------------------------------
// combine: row i (block r): row-side slots jt=0..r, col-side slots 16+it,
// it=r+1..15, centers from minc.
__global__ __launch_bounds__(256) void combine1(
    const float* __restrict__ ap_part, const float* __restrict__ an_part,
    const float* __restrict__ minc, float* __restrict__ bsum) {
    __shared__ float sred[4];
    const int i = blockIdx.x * 256 + threadIdx.x;
    const int r = i >> 8;
    float ap = -1e30f, an = 1e30f;
    for (int jt = 0; jt <= r; ++jt) {
        ap = fmaxf(ap, ap_part[(size_t)jt * N_ + i]);
        an = fminf(an, an_part[(size_t)jt * N_ + i]);
    }
    for (int itb = r + 1; itb < 16; ++itb) {
        ap = fmaxf(ap, ap_part[(size_t)(16 + itb) * N_ + i]);
        an = fminf(an, an_part[(size_t)(16 + itb) * N_ + i]);
    }
    float dan = (an < 1e29f) ? an : (ap + 1.0f);
    dan = fminf(dan, minc[i]);
    float term = fmaxf(0.0f, 1.0f + ap - dan);
#pragma unroll
    for (int m = 32; m > 0; m >>= 1) term += __shfl_xor(term, m);
    if ((threadIdx.x & 63) == 0) sred[threadIdx.x >> 6] = term;
    __syncthreads();
    if (threadIdx.x == 0)
        bsum[blockIdx.x] = sred[0] + sred[1] + sred[2] + sred[3];
}

__global__ void finalize(const float* __restrict__ bsum, float* __restrict__ out) {
    if (threadIdx.x == 0) {
        float s = 0.f;
        for (int b = 0; b < N_ / 256; ++b) s += bsum[b];
        out[0] = s / (float)N_;
    }
}

// ---------------------------------------------------------------------------
extern "C" void kernel_launch(void* const* d_in, const int* in_sizes, int n_in,
                              void* d_out, int out_size, void* d_ws, size_t ws_size,
                              hipStream_t stream) {
    const float* X = (const float*)d_in[0];
    const int* T = (const int*)d_in[1];
    const float* C = (const float*)d_in[2];
    float* out = (float*)d_out;

    float* ws = (float*)d_ws;
    float* sqc = ws;                                   // 4352
    float* bsum = ws + 4352;                           // 16
    float* minc = ws + 4368;                           // 4096
    unsigned short* XC = (unsigned short*)(ws + 8464); // 4352*768 us = 1,671,168 fl
    float* ap_part = ws + 8464 + 1671168;              // 32*4096 = 131072
    float* an_part = ap_part + 131072;                 // 131072  (end ~7.7 MB)

    pre_kernel<<<NROWS / 4, 256, 0, stream>>>(X, C, sqc, XC);
    mfma256<<<NBLK, 512, 0, stream>>>(XC, T, sqc, ap_part, an_part, minc);
    combine1<<<N_ / 256, 256, 0, stream>>>(ap_part, an_part, minc, bsum);
    finalize<<<1, 64, 0, stream>>>(bsum, out);
}

// Round 6
// 61.685 us; speedup vs baseline: 9.4039x; 1.0729x over previous
//
#include <hip/hip_runtime.h>
#include <math.h>

#define N_ 4096
#define D_ 768
#define P_ 100
#define PPAD 128
#define NT 24                   /* K-tiles: 768 / 32 */
#define NTRI 528                /* lower-tri 128x128 tile pairs incl diag */
#define NBLK 560                /* 528 + 32 center tiles */

typedef __attribute__((ext_vector_type(8))) short short8;
typedef __attribute__((ext_vector_type(4))) float f32x4;

typedef const __attribute__((address_space(1))) void* gld_src_t;
typedef __attribute__((address_space(3))) void* gld_dst_t;
#define GLOAD16(g, d) __builtin_amdgcn_global_load_lds((gld_src_t)(g), (gld_dst_t)(d), 16, 0, 0)

#define WAITVM4() asm volatile("s_waitcnt vmcnt(4)" ::: "memory")
#define WAITVM0() asm volatile("s_waitcnt vmcnt(0)" ::: "memory")
static __device__ __forceinline__ void barrier_fenced() {
    asm volatile("" ::: "memory");
    __builtin_amdgcn_s_barrier();
    asm volatile("" ::: "memory");
}

// float -> bf16 (RNE)
__device__ inline unsigned short f2bf(float f) {
    union { float f; unsigned int u; } v; v.f = f;
    unsigned int u = v.u + 0x7fffu + ((v.u >> 16) & 1u);
    return (unsigned short)(u >> 16);
}

// ---------------------------------------------------------------------------
// pre: one wave per row. sq[i]=||x_i||^2 fp32; Xbf=bf16(X); cnbf=bf16(row-
// normalized C, padded to 128 rows of zeros); csq fp32 (1e30 for pads).
__global__ __launch_bounds__(256) void pre_kernel(
    const float* __restrict__ X, const float* __restrict__ C,
    float* __restrict__ sq, unsigned short* __restrict__ Xbf,
    unsigned short* __restrict__ cnbf, float* __restrict__ csq) {
    const int gw = blockIdx.x * 4 + (threadIdx.x >> 6);
    const int l = threadIdx.x & 63;
    if (gw < N_) {
        const float4* x4 = (const float4*)(X + (size_t)gw * D_);
        short4* ob = (short4*)(Xbf + (size_t)gw * D_);
        float s = 0.f;
#pragma unroll
        for (int c = 0; c < 3; ++c) {
            float4 v = x4[c * 64 + l];
            s = fmaf(v.x, v.x, fmaf(v.y, v.y, fmaf(v.z, v.z, fmaf(v.w, v.w, s))));
            short4 o;
            o.x = (short)f2bf(v.x); o.y = (short)f2bf(v.y);
            o.z = (short)f2bf(v.z); o.w = (short)f2bf(v.w);
            ob[c * 64 + l] = o;
        }
#pragma unroll
        for (int m = 1; m < 64; m <<= 1) s += __shfl_xor(s, m);
        if (l == 0) sq[gw] = s;
    } else {
        const int p = gw - N_;
        if (p >= PPAD) return;
        short4* ob = (short4*)(cnbf + (size_t)p * D_);
        if (p < P_) {
            const float4* c4 = (const float4*)(C + (size_t)p * D_);
            float4 v[3];
            float s = 0.f;
#pragma unroll
            for (int c = 0; c < 3; ++c) {
                v[c] = c4[c * 64 + l];
                s = fmaf(v[c].x, v[c].x, fmaf(v[c].y, v[c].y,
                    fmaf(v[c].z, v[c].z, fmaf(v[c].w, v[c].w, s))));
            }
#pragma unroll
            for (int m = 1; m < 64; m <<= 1) s += __shfl_xor(s, m);
            float rn = 1.0f / sqrtf(s);
#pragma unroll
            for (int c = 0; c < 3; ++c) {
                short4 o;
                o.x = (short)f2bf(v[c].x * rn); o.y = (short)f2bf(v[c].y * rn);
                o.z = (short)f2bf(v[c].z * rn); o.w = (short)f2bf(v[c].w * rn);
                ob[c * 64 + l] = o;
            }
            if (l == 0) csq[p] = s * rn * rn;
        } else {
            short4 z; z.x = z.y = z.z = z.w = 0;
#pragma unroll
            for (int c = 0; c < 3; ++c) ob[c * 64 + l] = z;
            if (l == 0) csq[p] = 1e30f;
        }
    }
}

// ---------------------------------------------------------------------------
// MFMA kernel: 128x128 tile, BK=32, 3-buffer LDS ring, counted vmcnt(4),
// raw barriers, zero-conflict XOR-swizzled LDS. Symmetric: only lower-tri
// tiles (jt<=it); off-diag tiles fold row-side AND col-side reductions.
// Slots (wc-folded via LDS): row-side jt (0..31); col-side 32+it (33..63).
__global__ __launch_bounds__(256, 3) void mfma_kernel(
    const unsigned short* __restrict__ Xbf, const unsigned short* __restrict__ cnbf,
    const int* __restrict__ T, const float* __restrict__ sq,
    const float* __restrict__ csq,
    float* __restrict__ ap_part, float* __restrict__ an_part,
    float* __restrict__ minc) {
    __shared__ __align__(16) unsigned short lds[3 * 8192];   // 48 KB

    const int tid = threadIdx.x;
    const int l = tid & 63;
    const int w = tid >> 6;       // wave 0..3
    const int wr = w >> 1;        // wave row (0/1)
    const int wc = w & 1;         // wave col (0/1)

    // bijective XCD swizzle: 560 = 8 * 70
    const int orig = blockIdx.x;
    const int bid = (orig & 7) * 70 + (orig >> 3);
    int it, jt;
    if (bid < NTRI) {
        int t = (int)((sqrtf(8.0f * bid + 1.0f) - 1.0f) * 0.5f);
        t += ((t + 1) * (t + 2) / 2 <= bid);
        t -= (t * (t + 1) / 2 > bid);
        it = t; jt = bid - t * (t + 1) / 2;        // jt <= it
    } else { it = bid - NTRI; jt = 32; }
    const bool is_center = (jt == 32);
    const bool is_diag = (it == jt);
    const int i0 = it * 128;
    const int j0 = is_center ? 0 : jt * 128;
    const unsigned short* __restrict__ Bmat = is_center ? cnbf : Xbf;

    // ---- staging addressing (verified zero-conflict pattern) ----
    const int srow = tid >> 2;                                  // 0..63
    const int scol = ((tid & 3) * 8) ^ (((srow & 6) >> 1) << 3);
    const unsigned short* gA0 = Xbf + (size_t)(i0 + srow) * D_ + scol;
    const unsigned short* gA1 = gA0 + (size_t)64 * D_;
    const unsigned short* gB0 = Bmat + (size_t)(j0 + srow) * D_ + scol;
    const unsigned short* gB1 = gB0 + (size_t)64 * D_;
    const int dA0 = w * 512, dA1 = 2048 + w * 512;
    const int dB0 = 4096 + w * 512, dB1 = 6144 + w * 512;

    // ---- fragment read addressing (swizzled, matches stage flip) ----
    const int col = l & 15;
    const int hi = l >> 4;
    const int rko = (hi * 8) ^ ((l & 6) << 2);
    const int aro = (wr * 64 + col) * 32 + rko;
    const int bro = 4096 + (wc * 64 + col) * 32 + rko;

    f32x4 acc[4][4];
#pragma unroll
    for (int m = 0; m < 4; ++m)
#pragma unroll
        for (int n = 0; n < 4; ++n) acc[m][n] = (f32x4){0.f, 0.f, 0.f, 0.f};

#define STAGE(t)                                                     \
    do {                                                             \
        const int bo_ = ((t) % 3) * 8192;                            \
        const int ke_ = (t) * 32;                                    \
        GLOAD16(gA0 + ke_, &lds[bo_ + dA0]);                         \
        GLOAD16(gA1 + ke_, &lds[bo_ + dA1]);                         \
        GLOAD16(gB0 + ke_, &lds[bo_ + dB0]);                         \
        GLOAD16(gB1 + ke_, &lds[bo_ + dB1]);                         \
    } while (0)

    STAGE(0);
    STAGE(1);
    WAITVM4();
    barrier_fenced();

    int bo = 0;
    for (int t = 0; t < NT; ++t) {
        if (t + 2 < NT) STAGE(t + 2);
        const unsigned short* Lb = &lds[bo * 8192];
        short8 a[4], b[4];
#pragma unroll
        for (int m = 0; m < 4; ++m)
            a[m] = *reinterpret_cast<const short8*>(Lb + aro + m * 512);
#pragma unroll
        for (int n = 0; n < 4; ++n)
            b[n] = *reinterpret_cast<const short8*>(Lb + bro + n * 512);
        __builtin_amdgcn_s_setprio(1);
#pragma unroll
        for (int m = 0; m < 4; ++m)
#pragma unroll
            for (int n = 0; n < 4; ++n)
                acc[m][n] = __builtin_amdgcn_mfma_f32_16x16x32_bf16(a[m], b[n], acc[m][n], 0, 0, 0);
        __builtin_amdgcn_s_setprio(0);
        if (t < NT - 1) {
            if (t + 2 < NT) WAITVM4();
            else WAITVM0();
            barrier_fenced();
        }
        bo = (bo == 2) ? 0 : bo + 1;
    }
#undef STAGE

    // ---------------- epilogue -------------------------------------------
    // C/D layout: col = lane&15, row = (lane>>4)*4 + reg
    float* lf = (float*)lds;           // ring LDS is free after this sync
    __syncthreads();

    if (!is_center) {
        float sqj[4]; int tj[4];
#pragma unroll
        for (int n = 0; n < 4; ++n) {
            int j = j0 + wc * 64 + n * 16 + col;
            sqj[n] = sq[j];
            tj[n] = T[j];
        }
        float apC[4], anC[4];
#pragma unroll
        for (int n = 0; n < 4; ++n) { apC[n] = -1e30f; anC[n] = 1e30f; }

#pragma unroll
        for (int m = 0; m < 4; ++m) {
#pragma unroll
            for (int r = 0; r < 4; ++r) {
                const int lrow = wr * 64 + m * 16 + hi * 4 + r;   // 0..127
                const int i = i0 + lrow;
                float sqi = sq[i];
                int ti = T[i];
                float apR = -1e30f, anR = 1e30f;
#pragma unroll
                for (int n = 0; n < 4; ++n) {
                    float d2 = sqi + sqj[n] - 2.0f * acc[m][n][r];
                    float d = sqrtf(fmaxf(d2, 1e-12f));
                    bool same = (tj[n] == ti);
                    apR = same ? fmaxf(apR, d) : apR;
                    anR = same ? anR : fminf(anR, d);
                    apC[n] = same ? fmaxf(apC[n], d) : apC[n];
                    anC[n] = same ? anC[n] : fminf(anC[n], d);
                }
#pragma unroll
                for (int msk = 1; msk < 16; msk <<= 1) {
                    apR = fmaxf(apR, __shfl_xor(apR, msk));
                    anR = fminf(anR, __shfl_xor(anR, msk));
                }
                if (col == 0) {
                    lf[wc * 128 + lrow] = apR;          // [0..255]
                    lf[256 + wc * 128 + lrow] = anR;    // [256..511]
                }
            }
        }
        __syncthreads();
        if (tid < 128) {
            float a = fmaxf(lf[tid], lf[128 + tid]);
            float b = fminf(lf[256 + tid], lf[384 + tid]);
            ap_part[(size_t)jt * N_ + i0 + tid] = a;
            an_part[(size_t)jt * N_ + i0 + tid] = b;
        }

        // col-side: fold over rows; off-diagonal tiles only
        if (!is_diag) {
            __syncthreads();
#pragma unroll
            for (int n = 0; n < 4; ++n) {
                apC[n] = fmaxf(apC[n], __shfl_xor(apC[n], 16));
                apC[n] = fmaxf(apC[n], __shfl_xor(apC[n], 32));
                anC[n] = fminf(anC[n], __shfl_xor(anC[n], 16));
                anC[n] = fminf(anC[n], __shfl_xor(anC[n], 32));
                if (hi == 0) {
                    int jl = wc * 64 + n * 16 + col;            // 0..127
                    lf[wr * 128 + jl] = apC[n];
                    lf[256 + wr * 128 + jl] = anC[n];
                }
            }
            __syncthreads();
            if (tid < 128) {
                float a = fmaxf(lf[tid], lf[128 + tid]);
                float b = fminf(lf[256 + tid], lf[384 + tid]);
                ap_part[(size_t)(32 + it) * N_ + j0 + tid] = a;
                an_part[(size_t)(32 + it) * N_ + j0 + tid] = b;
            }
        }
    } else {
        float sqj[4];
#pragma unroll
        for (int n = 0; n < 4; ++n) sqj[n] = csq[wc * 64 + n * 16 + col];
#pragma unroll
        for (int m = 0; m < 4; ++m) {
#pragma unroll
            for (int r = 0; r < 4; ++r) {
                const int lrow = wr * 64 + m * 16 + hi * 4 + r;
                const int i = i0 + lrow;
                float sqi = sq[i];
                float mc = 1e30f;
#pragma unroll
                for (int n = 0; n < 4; ++n) {
                    float d2 = sqi + sqj[n] - 2.0f * acc[m][n][r];
                    float d = fmaxf(sqrtf(fmaxf(d2, 0.0f)), 1e-12f);
                    mc = fminf(mc, d);
                }
#pragma unroll
                for (int msk = 1; msk < 16; msk <<= 1)
                    mc = fminf(mc, __shfl_xor(mc, msk));
                if (col == 0) lf[wc * 128 + lrow] = mc;
            }
        }
        __syncthreads();
        if (tid < 128) minc[i0 + tid] = fminf(lf[tid], lf[128 + tid]);
    }
}

// ---------------------------------------------------------------------------
// combine: row i in band r=i>>7: row-side slots jt=0..r, col-side slots
// 32+it2 for it2=r+1..31, plus center minc[i].
__global__ __launch_bounds__(256) void combine1(
    const float* __restrict__ ap_part, const float* __restrict__ an_part,
    const float* __restrict__ minc, float* __restrict__ bsum) {
    __shared__ float sred[4];
    const int i = blockIdx.x * 256 + threadIdx.x;
    const int r = i >> 7;
    float ap = -1e30f, an = 1e30f;
    for (int jt = 0; jt <= r; ++jt) {
        ap = fmaxf(ap, ap_part[(size_t)jt * N_ + i]);
        an = fminf(an, an_part[(size_t)jt * N_ + i]);
    }
    for (int it2 = r + 1; it2 < 32; ++it2) {
        ap = fmaxf(ap, ap_part[(size_t)(32 + it2) * N_ + i]);
        an = fminf(an, an_part[(size_t)(32 + it2) * N_ + i]);
    }
    float dan = (an < 1e29f) ? an : (ap + 1.0f);
    dan = fminf(dan, minc[i]);
    float term = fmaxf(0.0f, 1.0f + ap - dan);
#pragma unroll
    for (int m = 32; m > 0; m >>= 1) term += __shfl_xor(term, m);
    if ((threadIdx.x & 63) == 0) sred[threadIdx.x >> 6] = term;
    __syncthreads();
    if (threadIdx.x == 0)
        bsum[blockIdx.x] = sred[0] + sred[1] + sred[2] + sred[3];
}

__global__ void finalize(const float* __restrict__ bsum, float* __restrict__ out) {
    if (threadIdx.x == 0) {
        float s = 0.f;
        for (int b = 0; b < N_ / 256; ++b) s += bsum[b];
        out[0] = s / (float)N_;
    }
}

// ---------------------------------------------------------------------------
// Workspace layout (floats; audited):
//   sq      : [0,        4096)
//   csq     : [4096,     4224)
//   minc    : [4224,     8320)
//   bsum    : [8320,     8336)
//   Xbf     : [8336,     1581200)   4096*768 ushorts = 1,572,864 floats
//   cnbf    : [1581200,  1630352)   128*768 ushorts  =    49,152 floats
//   ap_part : [1630352,  1892496)   64*4096 floats
//   an_part : [1892496,  2154640)   64*4096 floats
//   total 2,154,640 floats = 8.62 MB  (R2's 8.64 MB layout worked)
extern "C" void kernel_launch(void* const* d_in, const int* in_sizes, int n_in,
                              void* d_out, int out_size, void* d_ws, size_t ws_size,
                              hipStream_t stream) {
    const float* X = (const float*)d_in[0];
    const int* T = (const int*)d_in[1];
    const float* C = (const float*)d_in[2];
    float* out = (float*)d_out;

    float* ws = (float*)d_ws;
    float* sq = ws;
    float* csq = ws + 4096;
    float* minc = ws + 4224;
    float* bsum = ws + 8320;
    unsigned short* Xbf = (unsigned short*)(ws + 8336);
    unsigned short* cnbf = (unsigned short*)(ws + 1581200);
    float* ap_part = ws + 1630352;
    float* an_part = ws + 1892496;

    pre_kernel<<<(N_ + PPAD) / 4, 256, 0, stream>>>(X, C, sq, Xbf, cnbf, csq);
    mfma_kernel<<<NBLK, 256, 0, stream>>>(Xbf, cnbf, T, sq, csq, ap_part, an_part, minc);
    combine1<<<N_ / 256, 256, 0, stream>>>(ap_part, an_part, minc, bsum);
    finalize<<<1, 64, 0, stream>>>(bsum, out);
}